// Round 9
// baseline (3325.650 us; speedup 1.0000x reference)
//
#include <hip/hip_runtime.h>

// RVQ v9: small independent blocks for latency hiding.
// 256-thr/4-wave blocks, BR=16 rows; per wave 256 codes x 16 rows (acc[16] f32x4
// in AGPRs). 3 blocks/CU concurrent. rh-only bf16 GEMM (K=256), packed-u64
// atomicMin argmin, guaranteed-margin exact rescue (semantics unchanged).
// x: [16,4096,256] f32 ; emb: [8,1024,256] f32
// out: [quantized 16777216][loss 1][indices-as-float 524288]
// ws:  [packE 4MB bf16][e2 8192 f32][lossPart 4096 f32]

#define NROWS 65536
#define DDIM  256
#define KC    1024
#define QST   8
#define BR    16
#define MCAP  12

typedef __attribute__((ext_vector_type(8))) short short8;
typedef __attribute__((ext_vector_type(4))) float f32x4;
typedef unsigned int u32;
typedef unsigned long long u64;
typedef unsigned short u16;

__device__ __forceinline__ u16 f2bf(float f) {
  u32 b = __float_as_uint(f);
  return (u16)((b + 0x7FFFu + ((b >> 16) & 1u)) >> 16);
}
__device__ __forceinline__ u32 cvt_pk_bf16(float lo, float hi) {
  u32 d;
  asm("v_cvt_pk_bf16_f32 %0, %1, %2" : "=v"(d) : "v"(lo), "v"(hi));
  return d;
}
// byte offset of 16B unit u (0..31) of row's rh, XOR-swizzled (rows are 512B)
__device__ __forceinline__ u32 runit(int row, int u) {
  return (u32)(row * 512 + ((u ^ (row & 7)) << 4));
}
// monotone f32 -> u32 key (ascending float order == ascending unsigned order)
__device__ __forceinline__ u32 fkey(float v) {
  u32 b = __float_as_uint(v);
  return b ^ (0x80000000u | (u32)((int)b >> 31));
}
__device__ __forceinline__ u64 pkey(float v, int idx) {
  return ((u64)fkey(v) << 32) | (u32)idx;
}
__device__ __forceinline__ float unfkey(u32 m) {
  u32 b = (m & 0x80000000u) ? (m ^ 0x80000000u) : ~m;
  return __uint_as_float(b);
}

__global__ void e2_kernel(const float* __restrict__ emb, float* __restrict__ e2) {
  const int row  = blockIdx.x * 4 + (threadIdx.x >> 6);
  const int lane = threadIdx.x & 63;
  const float4 v = ((const float4*)(emb + (size_t)row * DDIM))[lane];
  float s = v.x * v.x + v.y * v.y + v.z * v.z + v.w * v.w;
  #pragma unroll
  for (int m = 32; m >= 1; m >>= 1) s += __shfl_xor(s, m);
  if (lane == 0) e2[row] = s;
}

// Pack eh into A-frag stream: slot t = (((qi*4+w)*8+ekt)*16+ci)*64+l:
//   code = 256w+16ci+(l&15), k = 32ekt+8*(l>>4)+j  (8 bf16 per slot)
__global__ void pack_kernel(const float* __restrict__ emb, u16* __restrict__ packE) {
  const int t  = blockIdx.x * 256 + threadIdx.x;   // 262144 slots
  const int l   = t & 63;
  const int ci  = (t >> 6) & 15;
  const int ekt = (t >> 10) & 7;
  const int w   = (t >> 13) & 3;
  const int qi  = t >> 15;
  const int code = 256 * w + 16 * ci + (l & 15);
  const int k    = 32 * ekt + 8 * (l >> 4);
  const float* src = emb + ((size_t)qi * KC + code) * DDIM + k;
  short8 v;
  #pragma unroll
  for (int j = 0; j < 8; ++j) v[j] = (short)f2bf(src[j]);
  *(short8*)(packE + (size_t)t * 8) = v;
}

__global__ __launch_bounds__(256, 6)
void rvq_kernel(const float* __restrict__ x, const float* __restrict__ emb,
                const char* __restrict__ packEb, const float* __restrict__ e2g,
                float* __restrict__ out, float* __restrict__ outIdx,
                float* __restrict__ lossPart)
{
  __shared__ __align__(16) u16 Rh[BR * 256];   // 8KB rh residual (swizzled)
  __shared__ u64   slotL[BR];                  // packed (d,idx) argmin slots
  __shared__ int   cntL[BR];
  __shared__ int   candL[BR][MCAP];            // 768B
  __shared__ float rnormL[BR];
  __shared__ float red[4];

  const int tid = threadIdx.x;
  const int w = tid >> 6, l = tid & 63;
  const int g = l >> 4, rb16 = l & 15;
  const int row = tid >> 4, sub = tid & 15;    // 16 rows x 16 threads
  const size_t rowBase = (size_t)blockIdx.x * BR;
  char* RhB = (char*)Rh;
  float lossAcc = 0.f;
  float r[16];                                 // f32 residual, d = 16*sub + i

  // ---- init: r = x slice; write rh to LDS; rnorm; reset slots ----
  {
    const float* xp = x + (rowBase + row) * DDIM + 16 * sub;
    float rn = 0.f;
    #pragma unroll
    for (int f = 0; f < 4; ++f) {
      f32x4 v = *(const f32x4*)(xp + 4 * f);
      r[4*f+0] = v.x; r[4*f+1] = v.y; r[4*f+2] = v.z; r[4*f+3] = v.w;
      rn += v.x*v.x + v.y*v.y + v.z*v.z + v.w*v.w;
    }
    uint4 h0, h1;
    h0.x = cvt_pk_bf16(r[0],  r[1]);  h0.y = cvt_pk_bf16(r[2],  r[3]);
    h0.z = cvt_pk_bf16(r[4],  r[5]);  h0.w = cvt_pk_bf16(r[6],  r[7]);
    h1.x = cvt_pk_bf16(r[8],  r[9]);  h1.y = cvt_pk_bf16(r[10], r[11]);
    h1.z = cvt_pk_bf16(r[12], r[13]); h1.w = cvt_pk_bf16(r[14], r[15]);
    *(uint4*)(RhB + runit(row, 2*sub))     = h0;
    *(uint4*)(RhB + runit(row, 2*sub + 1)) = h1;
    rn += __shfl_xor(rn, 1); rn += __shfl_xor(rn, 2);
    rn += __shfl_xor(rn, 4); rn += __shfl_xor(rn, 8);
    if (sub == 0) rnormL[row] = rn;
    if (tid < BR) { slotL[tid] = ~0ULL; cntL[tid] = 0; }
  }
  __syncthreads();

  for (int qi = 0; qi < QST; ++qi) {
    const float* e2q = e2g + qi * KC;

    // ---- GEMM: wave w covers codes [256w,256w+256) x 16 rows, K=256 ----
    f32x4 acc[16];
    #pragma unroll
    for (int a = 0; a < 16; ++a) acc[a] = (f32x4){0.f, 0.f, 0.f, 0.f};
    const char* src = packEb + ((size_t)(qi * 4 + w) << 17) + (size_t)l * 16;
    #pragma unroll
    for (int ekt = 0; ekt < 8; ++ekt) {
      const short8 Bf = *(const short8*)(RhB + runit(rb16, ekt * 4 + g));
      #pragma unroll
      for (int ci = 0; ci < 16; ++ci) {
        const short8 Af = *(const short8*)(src + ((ekt * 16 + ci) << 10));
        acc[ci] = __builtin_amdgcn_mfma_f32_16x16x32_bf16(Af, Bf, acc[ci], 0, 0, 0);
      }
    }

    // ---- scoring: per-thread lex-min (one row rb16), combine, atomicMin ----
    {
      float bv = 3.4e38f; int bi = 0;
      #pragma unroll
      for (int ci = 0; ci < 16; ++ci) {
        const int cb = 256 * w + 16 * ci + 4 * g;
        f32x4 e4 = *(const f32x4*)&e2q[cb];
        #pragma unroll
        for (int jj = 0; jj < 4; ++jj) {
          float d = fmaf(-2.f, acc[ci][jj], e4[jj]);
          if (d < bv) { bv = d; bi = cb + jj; }
        }
      }
      #pragma unroll
      for (int m = 16; m <= 32; m <<= 1) {
        float ov = __shfl_xor(bv, m); int oi = __shfl_xor(bi, m);
        if (ov < bv || (ov == bv && oi < bi)) { bv = ov; bi = oi; }
      }
      if (l < 16) atomicMin(&slotL[l], pkey(bv, bi));
    }
    __syncthreads();   // slots final

    // ---- candidates within guaranteed margin ----
    {
      const float d0  = unfkey((u32)(slotL[rb16] >> 32));
      const float thr = d0 + 0.36f * sqrtf(rnormL[rb16]) + 0.05f;
      #pragma unroll
      for (int ci = 0; ci < 16; ++ci) {
        const int cb = 256 * w + 16 * ci + 4 * g;
        f32x4 e4 = *(const f32x4*)&e2q[cb];
        #pragma unroll
        for (int jj = 0; jj < 4; ++jj) {
          float d = fmaf(-2.f, acc[ci][jj], e4[jj]);
          if (d <= thr) {
            int p = atomicAdd(&cntL[rb16], 1);
            if (p < MCAP) candL[rb16][p] = cb + jj;
          }
        }
      }
    }
    __syncthreads();   // cnt/cand final

    // ---- fused resolve + exact rescue + update (16 thr/row, group-internal) ----
    {
      const int cnt = cntL[row];
      int myidx;
      if (cnt == 1) {
        myidx = (int)(u32)(slotL[row] & 0xFFFFFFFFu);
      } else {
        float bd = 3.4e38f; int bi = 0x7fffffff;
        const int n = (cnt <= MCAP) ? cnt : KC;    // overflow -> full exact scan
        for (int k2 = 0; k2 < n; ++k2) {
          const int c = (cnt <= MCAP) ? candL[row][k2] : k2;
          const float* ep = emb + ((size_t)qi * KC + c) * DDIM + 16 * sub;
          float dot = 0.f;
          #pragma unroll
          for (int f = 0; f < 4; ++f) {
            f32x4 ev = *(const f32x4*)(ep + 4 * f);
            dot += r[4*f+0]*ev.x + r[4*f+1]*ev.y + r[4*f+2]*ev.z + r[4*f+3]*ev.w;
          }
          dot += __shfl_xor(dot, 1); dot += __shfl_xor(dot, 2);
          dot += __shfl_xor(dot, 4); dot += __shfl_xor(dot, 8);
          float d = e2q[c] - 2.f * dot;
          if (d < bd || (d == bd && c < bi)) { bd = d; bi = c; }
        }
        myidx = bi;   // uniform across the 16-thread row group
      }
      // update residual + loss + rh rewrite
      const float* ep = emb + ((size_t)qi * KC + myidx) * DDIM + 16 * sub;
      float ls = 0.f;
      #pragma unroll
      for (int f = 0; f < 4; ++f) {
        f32x4 ev = *(const f32x4*)(ep + 4 * f);
        r[4*f+0] -= ev.x; ls += r[4*f+0]*r[4*f+0];
        r[4*f+1] -= ev.y; ls += r[4*f+1]*r[4*f+1];
        r[4*f+2] -= ev.z; ls += r[4*f+2]*r[4*f+2];
        r[4*f+3] -= ev.w; ls += r[4*f+3]*r[4*f+3];
      }
      uint4 h0, h1;
      h0.x = cvt_pk_bf16(r[0],  r[1]);  h0.y = cvt_pk_bf16(r[2],  r[3]);
      h0.z = cvt_pk_bf16(r[4],  r[5]);  h0.w = cvt_pk_bf16(r[6],  r[7]);
      h1.x = cvt_pk_bf16(r[8],  r[9]);  h1.y = cvt_pk_bf16(r[10], r[11]);
      h1.z = cvt_pk_bf16(r[12], r[13]); h1.w = cvt_pk_bf16(r[14], r[15]);
      *(uint4*)(RhB + runit(row, 2*sub))     = h0;
      *(uint4*)(RhB + runit(row, 2*sub + 1)) = h1;
      lossAcc += ls;
      float rn = ls;
      rn += __shfl_xor(rn, 1); rn += __shfl_xor(rn, 2);
      rn += __shfl_xor(rn, 4); rn += __shfl_xor(rn, 8);
      if (sub == 0) {
        rnormL[row] = rn;
        outIdx[(rowBase + row) * QST + qi] = (float)myidx;
        slotL[row] = ~0ULL;        // reset for next stage (post-read, pre-barrier)
        cntL[row] = 0;
      }
    }
    __syncthreads();   // Rh/rnorm/resets visible before next GEMM+scoring
  }

  // ---- final: out = x - r_final ----
  {
    const float* xp = x + (rowBase + row) * DDIM + 16 * sub;
    float* op = out + (rowBase + row) * DDIM + 16 * sub;
    #pragma unroll
    for (int f = 0; f < 4; ++f) {
      f32x4 xv = *(const f32x4*)(xp + 4 * f);
      f32x4 o;
      o.x = xv.x - r[4*f+0]; o.y = xv.y - r[4*f+1];
      o.z = xv.z - r[4*f+2]; o.w = xv.w - r[4*f+3];
      *(f32x4*)(op + 4 * f) = o;
    }
  }

  // ---- deterministic per-block loss partial ----
  {
    float s = lossAcc;
    #pragma unroll
    for (int m = 32; m >= 1; m >>= 1) s += __shfl_xor(s, m);
    if (l == 0) red[w] = s;
    __syncthreads();
    if (tid == 0) lossPart[blockIdx.x] = red[0] + red[1] + red[2] + red[3];
  }
}

__global__ void loss_final(const float* __restrict__ part, float* __restrict__ outLoss) {
  __shared__ float buf[256];
  const int t = threadIdx.x;
  float s = 0.f;
  #pragma unroll
  for (int k = 0; k < 16; ++k) s += part[t + 256 * k];
  buf[t] = s;
  __syncthreads();
  for (int st = 128; st >= 1; st >>= 1) {
    if (t < st) buf[t] += buf[t + st];
    __syncthreads();
  }
  if (t == 0) *outLoss = buf[0] * (1.25f / 16777216.f);
}

extern "C" void kernel_launch(void* const* d_in, const int* in_sizes, int n_in,
                              void* d_out, int out_size, void* d_ws, size_t ws_size,
                              hipStream_t stream) {
  (void)in_sizes; (void)n_in; (void)out_size; (void)ws_size;
  const float* x   = (const float*)d_in[0];
  const float* emb = (const float*)d_in[1];
  float* out     = (float*)d_out;
  float* outLoss = out + (size_t)NROWS * DDIM;            // 16777216
  float* outIdx  = outLoss + 1;                           // indices as float
  char*  packE   = (char*)d_ws;                           // 4 MB bf16 A-frag stream
  float* e2      = (float*)(packE + (size_t)QST * 4 * 8 * 16 * 64 * 16);  // 8192 f32
  float* part    = e2 + QST * KC;                         // 4096 f32

  pack_kernel<<<dim3(1024), dim3(256), 0, stream>>>(emb, (u16*)packE);
  e2_kernel<<<dim3(QST * KC / 4), dim3(256), 0, stream>>>(emb, e2);
  rvq_kernel<<<dim3(NROWS / BR), dim3(256), 0, stream>>>(x, emb, packE, e2, out, outIdx, part);
  loss_final<<<dim3(1), dim3(256), 0, stream>>>(part, outLoss);
}

// Round 10
// 2321.046 us; speedup vs baseline: 1.4328x; 1.4328x over previous
//
#include <hip/hip_runtime.h>

// RVQ v10 = v9 structure with the register-tier fix: __launch_bounds__(256, 4).
// Unified-RF accounting (R7/R8/R9 evidence): live = acc(64 AGPR) + ~50 arch = 114.
// (256,6) capped at 85 -> 3.6GB spill; (256,4) caps at 128 -> fits, AND gives
// 4 independent blocks/CU for latency hiding (the R7/R8 mega-block flaw).
// x: [16,4096,256] f32 ; emb: [8,1024,256] f32
// out: [quantized 16777216][loss 1][indices-as-float 524288]
// ws:  [packE 4MB bf16][e2 8192 f32][lossPart 4096 f32]

#define NROWS 65536
#define DDIM  256
#define KC    1024
#define QST   8
#define BR    16
#define MCAP  12

typedef __attribute__((ext_vector_type(8))) short short8;
typedef __attribute__((ext_vector_type(4))) float f32x4;
typedef unsigned int u32;
typedef unsigned long long u64;
typedef unsigned short u16;

__device__ __forceinline__ u16 f2bf(float f) {
  u32 b = __float_as_uint(f);
  return (u16)((b + 0x7FFFu + ((b >> 16) & 1u)) >> 16);
}
__device__ __forceinline__ u32 cvt_pk_bf16(float lo, float hi) {
  u32 d;
  asm("v_cvt_pk_bf16_f32 %0, %1, %2" : "=v"(d) : "v"(lo), "v"(hi));
  return d;
}
// byte offset of 16B unit u (0..31) of row's rh, XOR-swizzled (rows are 512B)
__device__ __forceinline__ u32 runit(int row, int u) {
  return (u32)(row * 512 + ((u ^ (row & 7)) << 4));
}
// monotone f32 -> u32 key (ascending float order == ascending unsigned order)
__device__ __forceinline__ u32 fkey(float v) {
  u32 b = __float_as_uint(v);
  return b ^ (0x80000000u | (u32)((int)b >> 31));
}
__device__ __forceinline__ u64 pkey(float v, int idx) {
  return ((u64)fkey(v) << 32) | (u32)idx;
}
__device__ __forceinline__ float unfkey(u32 m) {
  u32 b = (m & 0x80000000u) ? (m ^ 0x80000000u) : ~m;
  return __uint_as_float(b);
}

__global__ void e2_kernel(const float* __restrict__ emb, float* __restrict__ e2) {
  const int row  = blockIdx.x * 4 + (threadIdx.x >> 6);
  const int lane = threadIdx.x & 63;
  const float4 v = ((const float4*)(emb + (size_t)row * DDIM))[lane];
  float s = v.x * v.x + v.y * v.y + v.z * v.z + v.w * v.w;
  #pragma unroll
  for (int m = 32; m >= 1; m >>= 1) s += __shfl_xor(s, m);
  if (lane == 0) e2[row] = s;
}

// Pack eh into A-frag stream: slot t = (((qi*4+w)*8+ekt)*16+ci)*64+l:
//   code = 256w+16ci+(l&15), k = 32ekt+8*(l>>4)+j  (8 bf16 per slot)
__global__ void pack_kernel(const float* __restrict__ emb, u16* __restrict__ packE) {
  const int t  = blockIdx.x * 256 + threadIdx.x;   // 262144 slots
  const int l   = t & 63;
  const int ci  = (t >> 6) & 15;
  const int ekt = (t >> 10) & 7;
  const int w   = (t >> 13) & 3;
  const int qi  = t >> 15;
  const int code = 256 * w + 16 * ci + (l & 15);
  const int k    = 32 * ekt + 8 * (l >> 4);
  const float* src = emb + ((size_t)qi * KC + code) * DDIM + k;
  short8 v;
  #pragma unroll
  for (int j = 0; j < 8; ++j) v[j] = (short)f2bf(src[j]);
  *(short8*)(packE + (size_t)t * 8) = v;
}

__global__ __launch_bounds__(256, 4)
void rvq_kernel(const float* __restrict__ x, const float* __restrict__ emb,
                const char* __restrict__ packEb, const float* __restrict__ e2g,
                float* __restrict__ out, float* __restrict__ outIdx,
                float* __restrict__ lossPart)
{
  __shared__ __align__(16) u16 Rh[BR * 256];   // 8KB rh residual (swizzled)
  __shared__ u64   slotL[BR];                  // packed (d,idx) argmin slots
  __shared__ int   cntL[BR];
  __shared__ int   candL[BR][MCAP];            // 768B
  __shared__ float rnormL[BR];
  __shared__ float red[4];

  const int tid = threadIdx.x;
  const int w = tid >> 6, l = tid & 63;
  const int g = l >> 4, rb16 = l & 15;
  const int row = tid >> 4, sub = tid & 15;    // 16 rows x 16 threads
  const size_t rowBase = (size_t)blockIdx.x * BR;
  char* RhB = (char*)Rh;
  float lossAcc = 0.f;
  float r[16];                                 // f32 residual, d = 16*sub + i

  // ---- init: r = x slice; write rh to LDS; rnorm; reset slots ----
  {
    const float* xp = x + (rowBase + row) * DDIM + 16 * sub;
    float rn = 0.f;
    #pragma unroll
    for (int f = 0; f < 4; ++f) {
      f32x4 v = *(const f32x4*)(xp + 4 * f);
      r[4*f+0] = v.x; r[4*f+1] = v.y; r[4*f+2] = v.z; r[4*f+3] = v.w;
      rn += v.x*v.x + v.y*v.y + v.z*v.z + v.w*v.w;
    }
    uint4 h0, h1;
    h0.x = cvt_pk_bf16(r[0],  r[1]);  h0.y = cvt_pk_bf16(r[2],  r[3]);
    h0.z = cvt_pk_bf16(r[4],  r[5]);  h0.w = cvt_pk_bf16(r[6],  r[7]);
    h1.x = cvt_pk_bf16(r[8],  r[9]);  h1.y = cvt_pk_bf16(r[10], r[11]);
    h1.z = cvt_pk_bf16(r[12], r[13]); h1.w = cvt_pk_bf16(r[14], r[15]);
    *(uint4*)(RhB + runit(row, 2*sub))     = h0;
    *(uint4*)(RhB + runit(row, 2*sub + 1)) = h1;
    rn += __shfl_xor(rn, 1); rn += __shfl_xor(rn, 2);
    rn += __shfl_xor(rn, 4); rn += __shfl_xor(rn, 8);
    if (sub == 0) rnormL[row] = rn;
    if (tid < BR) { slotL[tid] = ~0ULL; cntL[tid] = 0; }
  }
  __syncthreads();

  for (int qi = 0; qi < QST; ++qi) {
    const float* e2q = e2g + qi * KC;

    // ---- GEMM: wave w covers codes [256w,256w+256) x 16 rows, K=256 ----
    f32x4 acc[16];
    #pragma unroll
    for (int a = 0; a < 16; ++a) acc[a] = (f32x4){0.f, 0.f, 0.f, 0.f};
    const char* src = packEb + ((size_t)(qi * 4 + w) << 17) + (size_t)l * 16;
    #pragma unroll
    for (int ekt = 0; ekt < 8; ++ekt) {
      const short8 Bf = *(const short8*)(RhB + runit(rb16, ekt * 4 + g));
      #pragma unroll
      for (int ci = 0; ci < 16; ++ci) {
        const short8 Af = *(const short8*)(src + ((ekt * 16 + ci) << 10));
        acc[ci] = __builtin_amdgcn_mfma_f32_16x16x32_bf16(Af, Bf, acc[ci], 0, 0, 0);
      }
    }

    // ---- scoring: per-thread lex-min (one row rb16), combine, atomicMin ----
    {
      float bv = 3.4e38f; int bi = 0;
      #pragma unroll
      for (int ci = 0; ci < 16; ++ci) {
        const int cb = 256 * w + 16 * ci + 4 * g;
        f32x4 e4 = *(const f32x4*)&e2q[cb];
        #pragma unroll
        for (int jj = 0; jj < 4; ++jj) {
          float d = fmaf(-2.f, acc[ci][jj], e4[jj]);
          if (d < bv) { bv = d; bi = cb + jj; }
        }
      }
      #pragma unroll
      for (int m = 16; m <= 32; m <<= 1) {
        float ov = __shfl_xor(bv, m); int oi = __shfl_xor(bi, m);
        if (ov < bv || (ov == bv && oi < bi)) { bv = ov; bi = oi; }
      }
      if (l < 16) atomicMin(&slotL[l], pkey(bv, bi));
    }
    __syncthreads();   // slots final

    // ---- candidates within guaranteed margin ----
    {
      const float d0  = unfkey((u32)(slotL[rb16] >> 32));
      const float thr = d0 + 0.36f * sqrtf(rnormL[rb16]) + 0.05f;
      #pragma unroll
      for (int ci = 0; ci < 16; ++ci) {
        const int cb = 256 * w + 16 * ci + 4 * g;
        f32x4 e4 = *(const f32x4*)&e2q[cb];
        #pragma unroll
        for (int jj = 0; jj < 4; ++jj) {
          float d = fmaf(-2.f, acc[ci][jj], e4[jj]);
          if (d <= thr) {
            int p = atomicAdd(&cntL[rb16], 1);
            if (p < MCAP) candL[rb16][p] = cb + jj;
          }
        }
      }
    }
    __syncthreads();   // cnt/cand final

    // ---- fused resolve + exact rescue + update (16 thr/row, group-internal) ----
    {
      const int cnt = cntL[row];
      int myidx;
      if (cnt == 1) {
        myidx = (int)(u32)(slotL[row] & 0xFFFFFFFFu);
      } else {
        float bd = 3.4e38f; int bi = 0x7fffffff;
        const int n = (cnt <= MCAP) ? cnt : KC;    // overflow -> full exact scan
        for (int k2 = 0; k2 < n; ++k2) {
          const int c = (cnt <= MCAP) ? candL[row][k2] : k2;
          const float* ep = emb + ((size_t)qi * KC + c) * DDIM + 16 * sub;
          float dot = 0.f;
          #pragma unroll
          for (int f = 0; f < 4; ++f) {
            f32x4 ev = *(const f32x4*)(ep + 4 * f);
            dot += r[4*f+0]*ev.x + r[4*f+1]*ev.y + r[4*f+2]*ev.z + r[4*f+3]*ev.w;
          }
          dot += __shfl_xor(dot, 1); dot += __shfl_xor(dot, 2);
          dot += __shfl_xor(dot, 4); dot += __shfl_xor(dot, 8);
          float d = e2q[c] - 2.f * dot;
          if (d < bd || (d == bd && c < bi)) { bd = d; bi = c; }
        }
        myidx = bi;   // uniform across the 16-thread row group
      }
      // update residual + loss + rh rewrite
      const float* ep = emb + ((size_t)qi * KC + myidx) * DDIM + 16 * sub;
      float ls = 0.f;
      #pragma unroll
      for (int f = 0; f < 4; ++f) {
        f32x4 ev = *(const f32x4*)(ep + 4 * f);
        r[4*f+0] -= ev.x; ls += r[4*f+0]*r[4*f+0];
        r[4*f+1] -= ev.y; ls += r[4*f+1]*r[4*f+1];
        r[4*f+2] -= ev.z; ls += r[4*f+2]*r[4*f+2];
        r[4*f+3] -= ev.w; ls += r[4*f+3]*r[4*f+3];
      }
      uint4 h0, h1;
      h0.x = cvt_pk_bf16(r[0],  r[1]);  h0.y = cvt_pk_bf16(r[2],  r[3]);
      h0.z = cvt_pk_bf16(r[4],  r[5]);  h0.w = cvt_pk_bf16(r[6],  r[7]);
      h1.x = cvt_pk_bf16(r[8],  r[9]);  h1.y = cvt_pk_bf16(r[10], r[11]);
      h1.z = cvt_pk_bf16(r[12], r[13]); h1.w = cvt_pk_bf16(r[14], r[15]);
      *(uint4*)(RhB + runit(row, 2*sub))     = h0;
      *(uint4*)(RhB + runit(row, 2*sub + 1)) = h1;
      lossAcc += ls;
      float rn = ls;
      rn += __shfl_xor(rn, 1); rn += __shfl_xor(rn, 2);
      rn += __shfl_xor(rn, 4); rn += __shfl_xor(rn, 8);
      if (sub == 0) {
        rnormL[row] = rn;
        outIdx[(rowBase + row) * QST + qi] = (float)myidx;
        slotL[row] = ~0ULL;        // reset for next stage (post-read, pre-barrier)
        cntL[row] = 0;
      }
    }
    __syncthreads();   // Rh/rnorm/resets visible before next GEMM+scoring
  }

  // ---- final: out = x - r_final ----
  {
    const float* xp = x + (rowBase + row) * DDIM + 16 * sub;
    float* op = out + (rowBase + row) * DDIM + 16 * sub;
    #pragma unroll
    for (int f = 0; f < 4; ++f) {
      f32x4 xv = *(const f32x4*)(xp + 4 * f);
      f32x4 o;
      o.x = xv.x - r[4*f+0]; o.y = xv.y - r[4*f+1];
      o.z = xv.z - r[4*f+2]; o.w = xv.w - r[4*f+3];
      *(f32x4*)(op + 4 * f) = o;
    }
  }

  // ---- deterministic per-block loss partial ----
  {
    float s = lossAcc;
    #pragma unroll
    for (int m = 32; m >= 1; m >>= 1) s += __shfl_xor(s, m);
    if (l == 0) red[w] = s;
    __syncthreads();
    if (tid == 0) lossPart[blockIdx.x] = red[0] + red[1] + red[2] + red[3];
  }
}

__global__ void loss_final(const float* __restrict__ part, float* __restrict__ outLoss) {
  __shared__ float buf[256];
  const int t = threadIdx.x;
  float s = 0.f;
  #pragma unroll
  for (int k = 0; k < 16; ++k) s += part[t + 256 * k];
  buf[t] = s;
  __syncthreads();
  for (int st = 128; st >= 1; st >>= 1) {
    if (t < st) buf[t] += buf[t + st];
    __syncthreads();
  }
  if (t == 0) *outLoss = buf[0] * (1.25f / 16777216.f);
}

extern "C" void kernel_launch(void* const* d_in, const int* in_sizes, int n_in,
                              void* d_out, int out_size, void* d_ws, size_t ws_size,
                              hipStream_t stream) {
  (void)in_sizes; (void)n_in; (void)out_size; (void)ws_size;
  const float* x   = (const float*)d_in[0];
  const float* emb = (const float*)d_in[1];
  float* out     = (float*)d_out;
  float* outLoss = out + (size_t)NROWS * DDIM;            // 16777216
  float* outIdx  = outLoss + 1;                           // indices as float
  char*  packE   = (char*)d_ws;                           // 4 MB bf16 A-frag stream
  float* e2      = (float*)(packE + (size_t)QST * 4 * 8 * 16 * 64 * 16);  // 8192 f32
  float* part    = e2 + QST * KC;                         // 4096 f32

  pack_kernel<<<dim3(1024), dim3(256), 0, stream>>>(emb, (u16*)packE);
  e2_kernel<<<dim3(QST * KC / 4), dim3(256), 0, stream>>>(emb, e2);
  rvq_kernel<<<dim3(NROWS / BR), dim3(256), 0, stream>>>(x, emb, packE, e2, out, outIdx, part);
  loss_final<<<dim3(1), dim3(256), 0, stream>>>(part, outLoss);
}

// Round 11
// 1389.529 us; speedup vs baseline: 2.3934x; 1.6704x over previous
//
#include <hip/hip_runtime.h>

// RVQ v11: BR=64, 1024thr/16 waves (R8's clean codegen recipe), residual in
// swizzled LDS f32 (bit-exact updates), rh bf16 in LDS for MFMA, e2 in LDS.
// rh-only bf16 GEMM (K=256) + packed-u64 atomicMin argmin + guaranteed-margin
// exact rescue. 3 barriers/stage.
// x: [16,4096,256] f32 ; emb: [8,1024,256] f32
// out: [quantized 16777216][loss 1][indices-as-float 524288]
// ws:  [packE 4MB bf16][e2 8192 f32][lossPart 1024 f32]

#define NROWS 65536
#define DDIM  256
#define KC    1024
#define QST   8
#define BR    64
#define MCAP  12

typedef __attribute__((ext_vector_type(8))) short short8;
typedef __attribute__((ext_vector_type(4))) float f32x4;
typedef unsigned int u32;
typedef unsigned long long u64;
typedef unsigned short u16;

__device__ __forceinline__ u16 f2bf(float f) {
  u32 b = __float_as_uint(f);
  return (u16)((b + 0x7FFFu + ((b >> 16) & 1u)) >> 16);
}
__device__ __forceinline__ u32 cvt_pk_bf16(float lo, float hi) {
  u32 d;
  asm("v_cvt_pk_bf16_f32 %0, %1, %2" : "=v"(d) : "v"(lo), "v"(hi));
  return d;
}
// rh: byte offset of 16B unit u (0..31) of row's bf16 residual (rows 512B)
__device__ __forceinline__ u32 runit(int row, int u) {
  return (u32)(row * 512 + ((u ^ (row & 7)) << 4));
}
// res f32: byte offset of 16B unit u (0..63) of row's f32 residual (rows 1KB)
__device__ __forceinline__ u32 qunit(int row, int u) {
  return (u32)(row * 1024 + ((u ^ (row & 7)) << 4));
}
// monotone f32 -> u32 key
__device__ __forceinline__ u32 fkey(float v) {
  u32 b = __float_as_uint(v);
  return b ^ (0x80000000u | (u32)((int)b >> 31));
}
__device__ __forceinline__ u64 pkey(float v, int idx) {
  return ((u64)fkey(v) << 32) | (u32)idx;
}
__device__ __forceinline__ float unfkey(u32 m) {
  u32 b = (m & 0x80000000u) ? (m ^ 0x80000000u) : ~m;
  return __uint_as_float(b);
}

__global__ void e2_kernel(const float* __restrict__ emb, float* __restrict__ e2) {
  const int row  = blockIdx.x * 4 + (threadIdx.x >> 6);
  const int lane = threadIdx.x & 63;
  const float4 v = ((const float4*)(emb + (size_t)row * DDIM))[lane];
  float s = v.x * v.x + v.y * v.y + v.z * v.z + v.w * v.w;
  #pragma unroll
  for (int m = 32; m >= 1; m >>= 1) s += __shfl_xor(s, m);
  if (lane == 0) e2[row] = s;
}

// Pack eh into A-frag stream: slot t=((qi*16+W)*32+c)*64+l, c=(ekt*4+ci):
//   code = 64W+16ci+(l&15), k = 32ekt+8*(l>>4)+j  (8 bf16 per slot)
__global__ void pack_kernel(const float* __restrict__ emb, u16* __restrict__ packE) {
  const int t  = blockIdx.x * 256 + threadIdx.x;   // 262144 slots
  const int l  = t & 63;
  const int c  = (t >> 6) & 31;
  const int W  = (t >> 11) & 15;
  const int qi = t >> 15;
  const int code = 64 * W + 16 * (c & 3) + (l & 15);
  const int k    = 32 * (c >> 2) + 8 * (l >> 4);
  const float* src = emb + ((size_t)qi * KC + code) * DDIM + k;
  short8 v;
  #pragma unroll
  for (int j = 0; j < 8; ++j) v[j] = (short)f2bf(src[j]);
  *(short8*)(packE + (size_t)t * 8) = v;
}

__global__ __launch_bounds__(1024, 1)
void rvq_kernel(const float* __restrict__ x, const float* __restrict__ emb,
                const char* __restrict__ packEb, const float* __restrict__ e2g,
                float* __restrict__ out, float* __restrict__ outIdx,
                float* __restrict__ lossPart)
{
  __shared__ __align__(16) float Res[BR * 256];  // 64KB f32 residual (swizzled)
  __shared__ __align__(16) u16   Rh[BR * 256];   // 32KB bf16 residual (swizzled)
  __shared__ __align__(16) float e2L[QST * KC];  // 32KB all-stage ||e||^2
  __shared__ u64   slotL[BR];
  __shared__ int   cntL[BR];
  __shared__ int   candL[BR][MCAP];              // 3KB
  __shared__ float rnormL[BR];
  __shared__ float red[16];

  const int tid = threadIdx.x;
  const int w = tid >> 6, l = tid & 63;
  const int g = l >> 4, rb16 = l & 15;
  const int cg = w & 7, rg = w >> 3;             // wave: codes [128cg,+128) x rows [32rg,+32)
  const int row = tid >> 4, sub = tid & 15;      // 64 rows x 16 threads
  const size_t rowBase = (size_t)blockIdx.x * BR;
  char* RhB  = (char*)Rh;
  char* ResB = (char*)Res;
  float lossAcc = 0.f;

  // ---- preload all e2 (32KB) ----
  *(f32x4*)&e2L[4 * tid]        = *(const f32x4*)&e2g[4 * tid];
  *(f32x4*)&e2L[4 * tid + 4096] = *(const f32x4*)&e2g[4 * tid + 4096];

  // ---- init: res=x (LDS f32), rh=bf16(x), rnorm; reset slots ----
  {
    const float* xp = x + (rowBase + row) * DDIM + 16 * sub;
    f32x4 rr0 = *(const f32x4*)(xp);
    f32x4 rr1 = *(const f32x4*)(xp + 4);
    f32x4 rr2 = *(const f32x4*)(xp + 8);
    f32x4 rr3 = *(const f32x4*)(xp + 12);
    *(f32x4*)(ResB + qunit(row, 4 * sub + 0)) = rr0;
    *(f32x4*)(ResB + qunit(row, 4 * sub + 1)) = rr1;
    *(f32x4*)(ResB + qunit(row, 4 * sub + 2)) = rr2;
    *(f32x4*)(ResB + qunit(row, 4 * sub + 3)) = rr3;
    uint4 h0, h1;
    h0.x = cvt_pk_bf16(rr0.x, rr0.y); h0.y = cvt_pk_bf16(rr0.z, rr0.w);
    h0.z = cvt_pk_bf16(rr1.x, rr1.y); h0.w = cvt_pk_bf16(rr1.z, rr1.w);
    h1.x = cvt_pk_bf16(rr2.x, rr2.y); h1.y = cvt_pk_bf16(rr2.z, rr2.w);
    h1.z = cvt_pk_bf16(rr3.x, rr3.y); h1.w = cvt_pk_bf16(rr3.z, rr3.w);
    *(uint4*)(RhB + runit(row, 2 * sub))     = h0;
    *(uint4*)(RhB + runit(row, 2 * sub + 1)) = h1;
    float rn = rr0.x*rr0.x + rr0.y*rr0.y + rr0.z*rr0.z + rr0.w*rr0.w
             + rr1.x*rr1.x + rr1.y*rr1.y + rr1.z*rr1.z + rr1.w*rr1.w
             + rr2.x*rr2.x + rr2.y*rr2.y + rr2.z*rr2.z + rr2.w*rr2.w
             + rr3.x*rr3.x + rr3.y*rr3.y + rr3.z*rr3.z + rr3.w*rr3.w;
    rn += __shfl_xor(rn, 1); rn += __shfl_xor(rn, 2);
    rn += __shfl_xor(rn, 4); rn += __shfl_xor(rn, 8);
    if (sub == 0) rnormL[row] = rn;
    if (tid < BR) { slotL[tid] = ~0ULL; cntL[tid] = 0; }
  }
  __syncthreads();

  for (int qi = 0; qi < QST; ++qi) {
    const float* e2q = &e2L[qi * KC];

    // ---- GEMM: wave covers codes [128cg,+128) x rows [32rg,+32), K=256 ----
    f32x4 acc[8][2];
    #pragma unroll
    for (int a = 0; a < 8; ++a) {
      acc[a][0] = (f32x4){0.f, 0.f, 0.f, 0.f};
      acc[a][1] = (f32x4){0.f, 0.f, 0.f, 0.f};
    }
    const char* src = packEb + ((size_t)(qi * 16 + 2 * cg) << 15) + (size_t)l * 16;
    #pragma unroll
    for (int ekt = 0; ekt < 8; ++ekt) {
      short8 Bf0 = *(const short8*)(RhB + runit(32 * rg + rb16,      ekt * 4 + g));
      short8 Bf1 = *(const short8*)(RhB + runit(32 * rg + 16 + rb16, ekt * 4 + g));
      #pragma unroll
      for (int ci8 = 0; ci8 < 8; ++ci8) {
        const short8 Af = *(const short8*)(src + ((ci8 >> 2) << 15)
                                               + ((ekt * 4 + (ci8 & 3)) << 10));
        acc[ci8][0] = __builtin_amdgcn_mfma_f32_16x16x32_bf16(Af, Bf0, acc[ci8][0], 0, 0, 0);
        acc[ci8][1] = __builtin_amdgcn_mfma_f32_16x16x32_bf16(Af, Bf1, acc[ci8][1], 0, 0, 0);
      }
    }

    // ---- scoring: per-thread lex-min, 4-lane-g combine, packed atomicMin ----
    {
      float bv0 = 3.4e38f, bv1 = 3.4e38f; int bi0 = 0, bi1 = 0;
      #pragma unroll
      for (int ci8 = 0; ci8 < 8; ++ci8) {
        const int cb = 128 * cg + 64 * (ci8 >> 2) + 16 * (ci8 & 3) + 4 * g;
        f32x4 e4 = *(const f32x4*)&e2q[cb];
        #pragma unroll
        for (int jj = 0; jj < 4; ++jj) {
          float d0 = fmaf(-2.f, acc[ci8][0][jj], e4[jj]);
          float d1 = fmaf(-2.f, acc[ci8][1][jj], e4[jj]);
          if (d0 < bv0) { bv0 = d0; bi0 = cb + jj; }
          if (d1 < bv1) { bv1 = d1; bi1 = cb + jj; }
        }
      }
      #pragma unroll
      for (int m = 16; m <= 32; m <<= 1) {
        float ov0 = __shfl_xor(bv0, m); int oi0 = __shfl_xor(bi0, m);
        float ov1 = __shfl_xor(bv1, m); int oi1 = __shfl_xor(bi1, m);
        if (ov0 < bv0 || (ov0 == bv0 && oi0 < bi0)) { bv0 = ov0; bi0 = oi0; }
        if (ov1 < bv1 || (ov1 == bv1 && oi1 < bi1)) { bv1 = ov1; bi1 = oi1; }
      }
      if (l < 16) {
        atomicMin(&slotL[32 * rg + l],      pkey(bv0, bi0));
        atomicMin(&slotL[32 * rg + 16 + l], pkey(bv1, bi1));
      }
    }
    __syncthreads();   // slots final

    // ---- candidates within guaranteed margin ----
    {
      const int rw0 = 32 * rg + rb16, rw1 = rw0 + 16;
      const float thr0 = unfkey((u32)(slotL[rw0] >> 32)) + 0.36f * sqrtf(rnormL[rw0]) + 0.05f;
      const float thr1 = unfkey((u32)(slotL[rw1] >> 32)) + 0.36f * sqrtf(rnormL[rw1]) + 0.05f;
      #pragma unroll
      for (int ci8 = 0; ci8 < 8; ++ci8) {
        const int cb = 128 * cg + 64 * (ci8 >> 2) + 16 * (ci8 & 3) + 4 * g;
        f32x4 e4 = *(const f32x4*)&e2q[cb];
        #pragma unroll
        for (int jj = 0; jj < 4; ++jj) {
          float d0 = fmaf(-2.f, acc[ci8][0][jj], e4[jj]);
          float d1 = fmaf(-2.f, acc[ci8][1][jj], e4[jj]);
          if (d0 <= thr0) {
            int p = atomicAdd(&cntL[rw0], 1);
            if (p < MCAP) candL[rw0][p] = cb + jj;
          }
          if (d1 <= thr1) {
            int p = atomicAdd(&cntL[rw1], 1);
            if (p < MCAP) candL[rw1][p] = cb + jj;
          }
        }
      }
    }
    __syncthreads();   // cnt/cand final

    // ---- fused resolve + exact rescue + update (16 thr/row) ----
    {
      f32x4 rr0 = *(const f32x4*)(ResB + qunit(row, 4 * sub + 0));
      f32x4 rr1 = *(const f32x4*)(ResB + qunit(row, 4 * sub + 1));
      f32x4 rr2 = *(const f32x4*)(ResB + qunit(row, 4 * sub + 2));
      f32x4 rr3 = *(const f32x4*)(ResB + qunit(row, 4 * sub + 3));
      const int cnt = cntL[row];
      int myidx;
      if (cnt == 1) {
        myidx = (int)(u32)(slotL[row] & 0xFFFFFFFFu);
      } else {
        float bd = 3.4e38f; int bi = 0x7fffffff;
        const int n = (cnt <= MCAP) ? cnt : KC;    // overflow -> full exact scan
        for (int k2 = 0; k2 < n; ++k2) {
          const int c = (cnt <= MCAP) ? candL[row][k2] : k2;
          const float* ep = emb + ((size_t)qi * KC + c) * DDIM + 16 * sub;
          f32x4 e0 = *(const f32x4*)(ep);
          f32x4 e1 = *(const f32x4*)(ep + 4);
          f32x4 e2v = *(const f32x4*)(ep + 8);
          f32x4 e3 = *(const f32x4*)(ep + 12);
          float dot = rr0.x*e0.x + rr0.y*e0.y + rr0.z*e0.z + rr0.w*e0.w
                    + rr1.x*e1.x + rr1.y*e1.y + rr1.z*e1.z + rr1.w*e1.w
                    + rr2.x*e2v.x + rr2.y*e2v.y + rr2.z*e2v.z + rr2.w*e2v.w
                    + rr3.x*e3.x + rr3.y*e3.y + rr3.z*e3.z + rr3.w*e3.w;
          dot += __shfl_xor(dot, 1); dot += __shfl_xor(dot, 2);
          dot += __shfl_xor(dot, 4); dot += __shfl_xor(dot, 8);
          float d = e2q[c] - 2.f * dot;
          if (d < bd || (d == bd && c < bi)) { bd = d; bi = c; }
        }
        myidx = bi;   // uniform across the 16-thread row group
      }
      // update residual + loss + res/rh rewrite
      const float* ep = emb + ((size_t)qi * KC + myidx) * DDIM + 16 * sub;
      f32x4 e0 = *(const f32x4*)(ep);
      f32x4 e1 = *(const f32x4*)(ep + 4);
      f32x4 e2v = *(const f32x4*)(ep + 8);
      f32x4 e3 = *(const f32x4*)(ep + 12);
      rr0.x -= e0.x; rr0.y -= e0.y; rr0.z -= e0.z; rr0.w -= e0.w;
      rr1.x -= e1.x; rr1.y -= e1.y; rr1.z -= e1.z; rr1.w -= e1.w;
      rr2.x -= e2v.x; rr2.y -= e2v.y; rr2.z -= e2v.z; rr2.w -= e2v.w;
      rr3.x -= e3.x; rr3.y -= e3.y; rr3.z -= e3.z; rr3.w -= e3.w;
      float ls = rr0.x*rr0.x + rr0.y*rr0.y + rr0.z*rr0.z + rr0.w*rr0.w
               + rr1.x*rr1.x + rr1.y*rr1.y + rr1.z*rr1.z + rr1.w*rr1.w
               + rr2.x*rr2.x + rr2.y*rr2.y + rr2.z*rr2.z + rr2.w*rr2.w
               + rr3.x*rr3.x + rr3.y*rr3.y + rr3.z*rr3.z + rr3.w*rr3.w;
      *(f32x4*)(ResB + qunit(row, 4 * sub + 0)) = rr0;
      *(f32x4*)(ResB + qunit(row, 4 * sub + 1)) = rr1;
      *(f32x4*)(ResB + qunit(row, 4 * sub + 2)) = rr2;
      *(f32x4*)(ResB + qunit(row, 4 * sub + 3)) = rr3;
      uint4 h0, h1;
      h0.x = cvt_pk_bf16(rr0.x, rr0.y); h0.y = cvt_pk_bf16(rr0.z, rr0.w);
      h0.z = cvt_pk_bf16(rr1.x, rr1.y); h0.w = cvt_pk_bf16(rr1.z, rr1.w);
      h1.x = cvt_pk_bf16(rr2.x, rr2.y); h1.y = cvt_pk_bf16(rr2.z, rr2.w);
      h1.z = cvt_pk_bf16(rr3.x, rr3.y); h1.w = cvt_pk_bf16(rr3.z, rr3.w);
      *(uint4*)(RhB + runit(row, 2 * sub))     = h0;
      *(uint4*)(RhB + runit(row, 2 * sub + 1)) = h1;
      lossAcc += ls;
      float rn = ls;
      rn += __shfl_xor(rn, 1); rn += __shfl_xor(rn, 2);
      rn += __shfl_xor(rn, 4); rn += __shfl_xor(rn, 8);
      if (sub == 0) {
        rnormL[row] = rn;
        outIdx[(rowBase + row) * QST + qi] = (float)myidx;
        slotL[row] = ~0ULL;        // reset for next stage (post-read, pre-barrier)
        cntL[row] = 0;
      }
    }
    __syncthreads();   // Res/Rh/rnorm/resets visible before next GEMM+scoring
  }

  // ---- final: out = x - res_final ----
  {
    const float* xp = x + (rowBase + row) * DDIM + 16 * sub;
    float* op = out + (rowBase + row) * DDIM + 16 * sub;
    #pragma unroll
    for (int f = 0; f < 4; ++f) {
      f32x4 xv = *(const f32x4*)(xp + 4 * f);
      f32x4 rv = *(const f32x4*)(ResB + qunit(row, 4 * sub + f));
      f32x4 o;
      o.x = xv.x - rv.x; o.y = xv.y - rv.y;
      o.z = xv.z - rv.z; o.w = xv.w - rv.w;
      *(f32x4*)(op + 4 * f) = o;
    }
  }

  // ---- deterministic per-block loss partial ----
  {
    float s = lossAcc;
    #pragma unroll
    for (int m = 32; m >= 1; m >>= 1) s += __shfl_xor(s, m);
    if (l == 0) red[w] = s;
    __syncthreads();
    if (tid == 0) {
      float t2 = 0.f;
      #pragma unroll
      for (int wv = 0; wv < 16; ++wv) t2 += red[wv];
      lossPart[blockIdx.x] = t2;
    }
  }
}

__global__ void loss_final(const float* __restrict__ part, float* __restrict__ outLoss) {
  __shared__ float buf[256];
  const int t = threadIdx.x;
  float s = 0.f;
  #pragma unroll
  for (int k = 0; k < 4; ++k) s += part[t + 256 * k];
  buf[t] = s;
  __syncthreads();
  for (int st = 128; st >= 1; st >>= 1) {
    if (t < st) buf[t] += buf[t + st];
    __syncthreads();
  }
  if (t == 0) *outLoss = buf[0] * (1.25f / 16777216.f);
}

extern "C" void kernel_launch(void* const* d_in, const int* in_sizes, int n_in,
                              void* d_out, int out_size, void* d_ws, size_t ws_size,
                              hipStream_t stream) {
  (void)in_sizes; (void)n_in; (void)out_size; (void)ws_size;
  const float* x   = (const float*)d_in[0];
  const float* emb = (const float*)d_in[1];
  float* out     = (float*)d_out;
  float* outLoss = out + (size_t)NROWS * DDIM;            // 16777216
  float* outIdx  = outLoss + 1;                           // indices as float
  char*  packE   = (char*)d_ws;                           // 4 MB bf16 A-frag stream
  float* e2      = (float*)(packE + (size_t)QST * 16 * 32 * 1024);  // 8192 f32
  float* part    = e2 + QST * KC;                         // 1024 f32

  pack_kernel<<<dim3(1024), dim3(256), 0, stream>>>(emb, (u16*)packE);
  e2_kernel<<<dim3(QST * KC / 4), dim3(256), 0, stream>>>(emb, e2);
  rvq_kernel<<<dim3(NROWS / BR), dim3(1024), 0, stream>>>(x, emb, packE, e2, out, outIdx, part);
  loss_final<<<dim3(1), dim3(256), 0, stream>>>(part, outLoss);
}